// Round 6
// baseline (301.159 us; speedup 1.0000x reference)
//
#include <hip/hip_runtime.h>

#define N_NODE 10000
#define N_INST 50000
#define N_SVC  20000
#define NEDGE  200000
#define D      128
#define NTASK  200000   // total (relation,dst) rows

typedef unsigned short ushort_t;
typedef __attribute__((ext_vector_type(8))) short short8;
typedef __attribute__((ext_vector_type(4))) float f32x4;

__device__ __forceinline__ ushort_t f2bf(float f) {
  unsigned u = __float_as_uint(f);
  u += 0x7fffu + ((u >> 16) & 1u);   // round-to-nearest-even
  return (ushort_t)(u >> 16);
}
__device__ __forceinline__ float bf_lo(unsigned u) { return __uint_as_float(u << 16); }
__device__ __forceinline__ float bf_hi(unsigned u) { return __uint_as_float(u & 0xffff0000u); }

// async global->LDS, 16B per lane; LDS dst = wave-uniform base + lane*16
__device__ __forceinline__ void gload16(const ushort_t* g, ushort_t* l) {
  __builtin_amdgcn_global_load_lds((const __attribute__((address_space(1))) unsigned int*)g,
                                   (__attribute__((address_space(3))) unsigned int*)l,
                                   16, 0, 0);
}

// relation ids: 0:sc(svc->svc) 1:in(inst->node) 2:ni(node->inst) 3:ii(inst->inst) 4:si(svc->inst) 5:is(inst->svc)
// slots layout (2 edge-stream slices): [rel][slice][dst][cap]
#define SLOTS_TOT 11680000

__device__ __forceinline__ int task_base(int r) {
  const int tb[6] = {0, 20000, 30000, 80000, 130000, 180000};
  return tb[r];
}
__device__ __forceinline__ int od_base(int r) {
  const int ob[6] = {0, 20000, 70000, 80000, 130000, 150000};
  return ob[r];
}

// branchless 6-way select
__device__ __forceinline__ int sel6(int r, int a0, int a1, int a2, int a3, int a4, int a5) {
  int v = a0; v = r == 1 ? a1 : v; v = r == 2 ? a2 : v;
  v = r == 3 ? a3 : v; v = r == 4 ? a4 : v; v = r == 5 ? a5 : v; return v;
}

// ---------------- build: cnt-only LDS, DIRECT global slot stores ----------------
// R4's k_build staged the whole slot chunk in 132KB LDS (zero + dump phases,
// 1 block/CU) and used 2500-row chunks -> 98 full-stream rescans. Scattered
// u16 slot stores hit chunk regions (~120-300KB) that stay L2-resident, so
// direct stores cost the same writeback with no staging. LDS now = cnt only
// (50KB, 12500-row chunks): 17 chunks x 2 slices = 34 build blocks (4x fewer
// rescans) + 34 src-hist range blocks, uniform 50KB -> 2 blocks/CU.
// Unwritten slot entries hold garbage: aggregate only reads [0,deg) per slice
// and masks deg==0 rows (sl clamp + scale 0), so this is safe.
#define NB_BC 34
#define NB_HR 34
struct BuildArgs {
  const int* src[6]; const int* dst[6];
  int* od0; int* od1;            // out_deg partials per slice [NTASK]
  int* in_deg0; int* in_deg1;    // dst counts per slice [NTASK]
  ushort_t* slots;
};
__global__ __launch_bounds__(1024) void k_build(BuildArgs a) {
  __shared__ int cnt[12500];     // 50 KB
  int b = blockIdx.x;
  if (b < NB_BC) {
    int s = b & 1, bb = b >> 1;
    // chunk table (12500 dst rows each): sc 2, in 1, ni 4, ii 4, si 4, is 2
    int rel = (bb >= 2) + (bb >= 3) + (bb >= 7) + (bb >= 11) + (bb >= 15);
    int ci  = bb - sel6(rel, 0, 2, 3, 7, 11, 15);
    int nd  = sel6(rel, 20000, 10000, 50000, 50000, 50000, 20000);
    int cap = sel6(rel, 40, 64, 24, 24, 24, 40);
    int cof = sel6(rel, 0, 1600000, 2880000, 5280000, 7680000, 10080000);
    int ssz = sel6(rel, 800000, 640000, 1200000, 1200000, 1200000, 800000);
    int lo = ci * 12500;
    int n = nd - lo; n = n < 12500 ? n : 12500;
    for (int i = threadIdx.x; i < n; i += 1024) cnt[i] = 0;
    __syncthreads();
    const int4* d4 = (const int4*)a.dst[rel];
    const int4* s4 = (const int4*)a.src[rel];
    ushort_t* srow = a.slots + (size_t)cof + (size_t)s * ssz;
    int i1 = (s + 1) * (NEDGE / 8);                // half stream per slice
    for (int i = s * (NEDGE / 8) + threadIdx.x; i < i1; i += 1024) {
      int4 dv = d4[i];
      int4 sv = s4[i];
      int dd[4] = {dv.x, dv.y, dv.z, dv.w};
      int ss[4] = {sv.x, sv.y, sv.z, sv.w};
      #pragma unroll
      for (int j = 0; j < 4; j++) {
        int local = dd[j] - lo;
        if ((unsigned)local < (unsigned)n) {
          int p = atomicAdd(&cnt[local], 1);
          if (p < cap) srow[(size_t)dd[j] * cap + p] = (ushort_t)ss[j];
        }
      }
    }
    __syncthreads();
    int* outd = (s ? a.in_deg1 : a.in_deg0) + task_base(rel) + lo;
    for (int i = threadIdx.x; i < n; i += 1024) {
      int c = cnt[i]; outd[i] = c < cap ? c : cap;
    }
    return;
  }
  // src-side out_deg partial histogram: 12500-src ranges x 2 slices
  // ranges: sc 2, in 4, ni 1, ii 4, si 2, is 4  (17 x 2 = 34 blocks)
  int h = b - NB_BC;
  int s = h & 1, hi = h >> 1;
  int rel = (hi >= 2) + (hi >= 6) + (hi >= 7) + (hi >= 11) + (hi >= 13);
  int lo = (hi - sel6(rel, 0, 2, 6, 7, 11, 13)) * 12500;
  int ns = sel6(rel, 20000, 50000, 10000, 50000, 20000, 50000);
  int n = ns - lo; n = n < 12500 ? n : 12500;
  for (int i = threadIdx.x; i < n; i += 1024) cnt[i] = 0;
  __syncthreads();
  const int4* s4 = (const int4*)a.src[rel];
  int i1 = (s + 1) * (NEDGE / 8);
  for (int i = s * (NEDGE / 8) + threadIdx.x; i < i1; i += 1024) {
    int4 v = s4[i];
    int ss[4] = {v.x, v.y, v.z, v.w};
    #pragma unroll
    for (int j = 0; j < 4; j++) {
      int local = ss[j] - lo;
      if ((unsigned)local < (unsigned)n) atomicAdd(&cnt[local], 1);
    }
  }
  __syncthreads();
  int* out = (s ? a.od1 : a.od0) + od_base(rel) + lo;
  for (int i = threadIdx.x; i < n; i += 1024) out[i] = cnt[i];
}

// ---------------- convert: bf16 features + weight transpose + out_deg merge ----------------
struct ConvArgs {
  const float* f0; const float* f1; const float* f2;       // node, inst, svc
  ushort_t* xb0; ushort_t* xb1; ushort_t* xb2;
  const float* W[6];
  ushort_t* Wt_node; ushort_t* Wt_inst; ushort_t* Wt_svc;  // [n][k_cat] row-major
  const int* od0; const int* od1; int* out_deg;
};
__global__ __launch_bounds__(256) void k_convert(ConvArgs a) {
  const int F0 = N_NODE * D / 4, F1 = N_INST * D / 4, F2 = N_SVC * D / 4;
  const int NF = F0 + F1 + F2;        // 2,560,000
  const int WI = 6 * D * D;           // 98,304
  const int MI = NTASK / 4;           // 50,000 int4 merges
  const int total = NF + WI + MI;
  int stride = gridDim.x * 256;
  for (int tid = blockIdx.x * 256 + threadIdx.x; tid < total; tid += stride) {
    if (tid < NF) {
      const float* src; ushort_t* dst; int i;
      if (tid < F0)            { src = a.f0; dst = a.xb0; i = tid; }
      else if (tid < F0 + F1)  { src = a.f1; dst = a.xb1; i = tid - F0; }
      else                     { src = a.f2; dst = a.xb2; i = tid - F0 - F1; }
      float4 v = ((const float4*)src)[i];
      unsigned o0 = (unsigned)f2bf(v.x) | ((unsigned)f2bf(v.y) << 16);
      unsigned o1 = (unsigned)f2bf(v.z) | ((unsigned)f2bf(v.w) << 16);
      ((uint2*)dst)[i] = make_uint2(o0, o1);
    } else if (tid < NF + WI) {
      int wi = tid - NF;
      int r = wi >> 14, idx = wi & 16383;      // D*D = 16384
      int k = idx >> 7, n = idx & 127;
      const float* wp = a.W[0];
      wp = r == 1 ? a.W[1] : wp; wp = r == 2 ? a.W[2] : wp;
      wp = r == 3 ? a.W[3] : wp; wp = r == 4 ? a.W[4] : wp;
      wp = r == 5 ? a.W[5] : wp;
      float v = wp[k * D + n];
      ushort_t* t; int wstride, coff;
      switch (r) {
        case 0: t = a.Wt_svc;  wstride = 256; coff = 0;   break; // sc
        case 1: t = a.Wt_node; wstride = 128; coff = 0;   break; // in
        case 2: t = a.Wt_inst; wstride = 384; coff = 0;   break; // ni
        case 3: t = a.Wt_inst; wstride = 384; coff = 128; break; // ii
        case 4: t = a.Wt_inst; wstride = 384; coff = 256; break; // si
        default:t = a.Wt_svc;  wstride = 256; coff = 128; break; // is
      }
      t[n * wstride + coff + k] = f2bf(v);
    } else {
      int i = tid - NF - WI;
      int4 x = ((const int4*)a.od0)[i];
      int4 y = ((const int4*)a.od1)[i];
      ((int4*)a.out_deg)[i] = make_int4(x.x + y.x, x.y + y.y, x.z + y.z, x.w + y.w);
    }
  }
}

// ---------------- aggregation: one QUAD (16 lanes) per row, 4 rows per wave ----------------
// Inner loop pipelined 4-deep (R4). launch_bounds(256,8): request 8 waves/EU
// (32 waves/CU) — the gather is latency-bound; 58% occupancy was the cap.
struct AggArgs {
  const ushort_t* xb[3];  // 0 node, 1 inst, 2 svc (bf16, [n][128])
  const int* out_deg; const int* in_deg0; const int* in_deg1; const ushort_t* slots;
  ushort_t* agg_node; ushort_t* agg_inst; ushort_t* agg_svc;
};
__global__ __launch_bounds__(256, 8) void k_aggregate(AggArgs a) {
  int wave_g = (blockIdx.x << 2) + (threadIdx.x >> 6);
  int lane = threadIdx.x & 63;
  int q = lane >> 4, l = lane & 15;
  int t = (wave_g << 2) + q;
  if (t >= NTASK) t = NTASK - 1;          // tail quads duplicate last row (benign)

  int rel = (t >= 20000) + (t >= 30000) + (t >= 80000) + (t >= 130000) + (t >= 180000);
  int dst  = t - sel6(rel, 0, 20000, 30000, 80000, 130000, 180000);
  int cap  = sel6(rel, 40, 64, 24, 24, 24, 40);
  int cof  = sel6(rel, 0, 1600000, 2880000, 5280000, 7680000, 10080000);
  int ssz  = sel6(rel, 800000, 640000, 1200000, 1200000, 1200000, 800000);
  int odb  = sel6(rel, 0, 20000, 70000, 80000, 130000, 150000);
  int nsm1 = sel6(rel, 19999, 49999, 9999, 49999, 19999, 49999);
  int sp   = sel6(rel, 2, 1, 0, 1, 2, 1);
  const ushort_t* xb = a.xb[0];
  xb = sp == 1 ? a.xb[1] : xb;
  xb = sp == 2 ? a.xb[2] : xb;

  int d0 = a.in_deg0[t];
  int d1 = a.in_deg1[t];
  int deg = d0 + d1;                       // per-slice counts are cap-clamped
  int base0 = cof + dst * cap;             // slice-0 row
  int base1 = base0 + ssz;                 // slice-1 row
  int l8 = l * 8;                          // channel offset (ushort units)
  int qb = lane & 48;                      // quad's lane base for bpermute
  const ushort_t* xbl = xb + l8;

  // wave-max degree (quads iterate in lockstep; idle quads get scale 0)
  int dmax = deg;
  dmax = max(dmax, __shfl_xor(dmax, 16, 64));
  dmax = max(dmax, __shfl_xor(dmax, 32, 64));
  dmax = __builtin_amdgcn_readfirstlane(dmax);

  float acc[8];
  #pragma unroll
  for (int c = 0; c < 8; c++) acc[c] = 0.f;

#define ACC8(v, sc)                                  \
  do {                                               \
    acc[0] = fmaf(bf_lo((v).x), (sc), acc[0]);       \
    acc[1] = fmaf(bf_hi((v).x), (sc), acc[1]);       \
    acc[2] = fmaf(bf_lo((v).y), (sc), acc[2]);       \
    acc[3] = fmaf(bf_hi((v).y), (sc), acc[3]);       \
    acc[4] = fmaf(bf_lo((v).z), (sc), acc[4]);       \
    acc[5] = fmaf(bf_hi((v).z), (sc), acc[5]);       \
    acc[6] = fmaf(bf_lo((v).w), (sc), acc[6]);       \
    acc[7] = fmaf(bf_hi((v).w), (sc), acc[7]);       \
  } while (0)

  for (int i0 = 0; i0 < dmax; i0 += 16) {
    int nc = deg - i0;                     // this quad's remaining (may be <=0)
    int k = i0 + l;
    k = k < deg ? k : (deg ? deg - 1 : 0); // clamp into valid edge range
    int addr = k < d0 ? base0 + k : base1 + (k - d0);
    int sl = a.slots[addr];                // coalesced u16 within quad
    sl = sl < nsm1 ? sl : nsm1;            // guard garbage (deg==0 rows)
    int od = a.out_deg[odb + sl];          // od>=1 for any real edge
    float scv = (l < nc) ? rsqrtf((float)od) : 0.f;

    int cmax = dmax - i0; cmax = cmax < 16 ? cmax : 16;
    int i = 0;
    for (; i + 4 <= cmax; i += 4) {
      int s0 = __shfl(sl, qb + i,     64);
      int s1 = __shfl(sl, qb + i + 1, 64);
      int s2 = __shfl(sl, qb + i + 2, 64);
      int s3 = __shfl(sl, qb + i + 3, 64);
      float c0 = __shfl(scv, qb + i,     64);
      float c1 = __shfl(scv, qb + i + 1, 64);
      float c2 = __shfl(scv, qb + i + 2, 64);
      float c3 = __shfl(scv, qb + i + 3, 64);
      uint4 v0 = *(const uint4*)(xbl + (size_t)s0 * D);
      uint4 v1 = *(const uint4*)(xbl + (size_t)s1 * D);
      uint4 v2 = *(const uint4*)(xbl + (size_t)s2 * D);
      uint4 v3 = *(const uint4*)(xbl + (size_t)s3 * D);
      ACC8(v0, c0);
      ACC8(v1, c1);
      ACC8(v2, c2);
      ACC8(v3, c3);
    }
    for (; i < cmax; ++i) {
      int s = __shfl(sl, qb + i, 64);      // edge i of THIS quad's row
      float sc = __shfl(scv, qb + i, 64);
      uint4 v = *(const uint4*)(xbl + (size_t)s * D);
      ACC8(v, sc);
    }
  }
#undef ACC8

  float si = rsqrtf((float)(deg < 1 ? 1 : deg));
  ushort_t* o = a.agg_svc;                 // rel 0,5
  o = rel == 1 ? a.agg_node : o;
  o = (rel >= 2 && rel <= 4) ? a.agg_inst : o;
  int stride = sel6(rel, 256, 128, 384, 384, 384, 256);
  int coff   = sel6(rel, 0, 0, 0, 128, 256, 128);
  unsigned e0 = (unsigned)f2bf(acc[0] * si) | ((unsigned)f2bf(acc[1] * si) << 16);
  unsigned e1 = (unsigned)f2bf(acc[2] * si) | ((unsigned)f2bf(acc[3] * si) << 16);
  unsigned e2 = (unsigned)f2bf(acc[4] * si) | ((unsigned)f2bf(acc[5] * si) << 16);
  unsigned e3 = (unsigned)f2bf(acc[6] * si) | ((unsigned)f2bf(acc[7] * si) << 16);
  *(uint4*)(o + (size_t)dst * stride + coff + l8) = make_uint4(e0, e1, e2, e3);
}

// ---------------- fused GEMM + bias + mean + relu ----------------
struct GemmGroup {
  const ushort_t* A; const ushort_t* Wt;
  const float* b0; const float* b1; const float* b2;
  float inv_m; int M; int Kg; int out_base; int tile_begin;
};
struct GemmArgs { GemmGroup g[3]; float* out; };

__global__ __launch_bounds__(256) void k_gemm(GemmArgs ga) {
  int bid = blockIdx.x;
  int gi = (bid >= ga.g[2].tile_begin) ? 2 : (bid >= ga.g[1].tile_begin ? 1 : 0);
  GemmGroup g = ga.g[gi];
  int tile = bid - g.tile_begin;

  __shared__ __align__(16) ushort_t As[128 * 32];   // 8 KB: 128 rows x 32 k (64 B/row)
  __shared__ __align__(16) ushort_t Bs[128 * 32];
  __shared__ float bsum[128];

  if (threadIdx.x < 128) {
    float b = g.b0[threadIdx.x];
    if (g.b1) b += g.b1[threadIdx.x];
    if (g.b2) b += g.b2[threadIdx.x];
    bsum[threadIdx.x] = b;
  }

  int wave = threadIdx.x >> 6, lane = threadIdx.x & 63;
  int wm = (wave >> 1) * 64, wn = (wave & 1) * 64;
  int m16 = lane & 15, kq = lane >> 4;
  int row0 = tile * 128;

  int srow = (wave << 5) + (lane >> 2);              // local row this lane stages (q=0)
  int spg0 = (lane & 3) ^ (srow & 3);                // xor-swizzled global piece
  int ppA = (kq ^ (m16 & 3)) * 8;

  f32x4 acc[4][4] = {};

  for (int kc = 0; kc < g.Kg; kc += 32) {
    __syncthreads();
    #pragma unroll
    for (int qq = 0; qq < 2; qq++) {
      int rloc = srow + qq * 16;
      int grA = row0 + rloc; grA = grA < g.M ? grA : g.M - 1;
      gload16(g.A  + (size_t)grA * g.Kg + kc + spg0 * 8, &As[((wave << 5) + (qq << 4)) << 5]);
      gload16(g.Wt + (size_t)rloc * g.Kg + kc + spg0 * 8, &Bs[((wave << 5) + (qq << 4)) << 5]);
    }
    __syncthreads();
    short8 av[4], bv[4];
    #pragma unroll
    for (int i = 0; i < 4; i++) av[i] = *(const short8*)(&As[((wm + i * 16 + m16) << 5) + ppA]);
    #pragma unroll
    for (int j = 0; j < 4; j++) bv[j] = *(const short8*)(&Bs[((wn + j * 16 + m16) << 5) + ppA]);
    #pragma unroll
    for (int i = 0; i < 4; i++)
      #pragma unroll
      for (int j = 0; j < 4; j++)
        acc[i][j] = __builtin_amdgcn_mfma_f32_16x16x32_bf16(av[i], bv[j], acc[i][j], 0, 0, 0);
  }

  // epilogue: D[row=(lane>>4)*4+r][col=lane&15] per 16x16 tile
  #pragma unroll
  for (int i = 0; i < 4; i++) {
    #pragma unroll
    for (int j = 0; j < 4; j++) {
      int col = wn + j * 16 + m16;
      #pragma unroll
      for (int r = 0; r < 4; r++) {
        int row = wm + i * 16 + kq * 4 + r;
        int gr = row0 + row;
        if (gr < g.M) {
          float v = (acc[i][j][r] + bsum[col]) * g.inv_m;
          v = v > 0.f ? v : 0.f;
          ga.out[(size_t)(g.out_base + gr) * D + col] = v;
        }
      }
    }
  }
}

// ---------------- host ----------------
extern "C" void kernel_launch(void* const* d_in, const int* in_sizes, int n_in,
                              void* d_out, int out_size, void* d_ws, size_t ws_size,
                              hipStream_t stream) {
  const float* node_feat = (const float*)d_in[0];
  const float* inst_feat = (const float*)d_in[1];
  const float* svc_feat  = (const float*)d_in[2];
  const int* e_src[6]; const int* e_dst[6]; const float* W[6]; const float* B[6];
  for (int r = 0; r < 6; r++) {
    e_src[r] = (const int*)d_in[3 + 4 * r];
    e_dst[r] = (const int*)d_in[4 + 4 * r];
    W[r]     = (const float*)d_in[5 + 4 * r];
    B[r]     = (const float*)d_in[6 + 4 * r];
  }

  char* ws = (char*)d_ws;
  size_t off = 0;
  auto alloc = [&](size_t bytes) { char* p = ws + off; off += (bytes + 255) & ~(size_t)255; return p; };
  ushort_t* xb_node  = (ushort_t*)alloc((size_t)N_NODE * D * 2);
  ushort_t* xb_inst  = (ushort_t*)alloc((size_t)N_INST * D * 2);
  ushort_t* xb_svc   = (ushort_t*)alloc((size_t)N_SVC  * D * 2);
  ushort_t* Wt_node  = (ushort_t*)alloc(128 * 128 * 2);
  ushort_t* Wt_inst  = (ushort_t*)alloc(128 * 384 * 2);
  ushort_t* Wt_svc   = (ushort_t*)alloc(128 * 256 * 2);
  ushort_t* agg_node = (ushort_t*)alloc((size_t)N_NODE * 128 * 2);
  ushort_t* agg_inst = (ushort_t*)alloc((size_t)N_INST * 384 * 2);
  ushort_t* agg_svc  = (ushort_t*)alloc((size_t)N_SVC  * 256 * 2);
  int* in_deg0 = (int*)alloc(NTASK * 4);
  int* in_deg1 = (int*)alloc(NTASK * 4);
  int* od0     = (int*)alloc(NTASK * 4);
  int* od1     = (int*)alloc(NTASK * 4);
  int* out_deg = (int*)alloc(NTASK * 4);
  ushort_t* slots = (ushort_t*)alloc((size_t)SLOTS_TOT * 2);

  // 1. build: 34 direct-store dst-build blocks + 34 src-hist blocks (50KB LDS, 2/CU)
  {
    BuildArgs a;
    for (int r = 0; r < 6; r++) { a.src[r] = e_src[r]; a.dst[r] = e_dst[r]; }
    a.od0 = od0; a.od1 = od1; a.in_deg0 = in_deg0; a.in_deg1 = in_deg1; a.slots = slots;
    k_build<<<NB_BC + NB_HR, 1024, 0, stream>>>(a);
  }
  // 2. convert: full-occupancy streaming (features, weights, out_deg merge)
  {
    ConvArgs a;
    a.f0 = node_feat; a.f1 = inst_feat; a.f2 = svc_feat;
    a.xb0 = xb_node; a.xb1 = xb_inst; a.xb2 = xb_svc;
    for (int r = 0; r < 6; r++) a.W[r] = W[r];
    a.Wt_node = Wt_node; a.Wt_inst = Wt_inst; a.Wt_svc = Wt_svc;
    a.od0 = od0; a.od1 = od1; a.out_deg = out_deg;
    k_convert<<<2048, 256, 0, stream>>>(a);
  }
  // 3. aggregate: 4 rows per wave, 16 rows per block
  {
    AggArgs a;
    a.xb[0] = xb_node; a.xb[1] = xb_inst; a.xb[2] = xb_svc;
    a.out_deg = out_deg; a.in_deg0 = in_deg0; a.in_deg1 = in_deg1; a.slots = slots;
    a.agg_node = agg_node; a.agg_inst = agg_inst; a.agg_svc = agg_svc;
    k_aggregate<<<(NTASK + 15) / 16, 256, 0, stream>>>(a);
  }
  // 4. fused GEMM
  {
    GemmArgs ga;
    ga.out = (float*)d_out;
    int t_node = (N_NODE + 127) / 128;   // 79
    int t_inst = (N_INST + 127) / 128;   // 391
    int t_svc  = (N_SVC  + 127) / 128;   // 157
    ga.g[0] = { agg_node, Wt_node, B[1], nullptr, nullptr, 1.0f,        N_NODE, 128, 0,               0 };
    ga.g[1] = { agg_inst, Wt_inst, B[2], B[3],    B[4],    1.0f / 3.0f, N_INST, 384, N_NODE,          t_node };
    ga.g[2] = { agg_svc,  Wt_svc,  B[0], B[5],    nullptr, 0.5f,        N_SVC,  256, N_NODE + N_INST, t_node + t_inst };
    k_gemm<<<t_node + t_inst + t_svc, 256, 0, stream>>>(ga);
  }
}

// Round 7
// 226.893 us; speedup vs baseline: 1.3273x; 1.3273x over previous
//
#include <hip/hip_runtime.h>

#define N_NODE 10000
#define N_INST 50000
#define N_SVC  20000
#define NEDGE  200000
#define D      128
#define NTASK  200000   // total (relation,dst) rows

typedef unsigned short ushort_t;
typedef __attribute__((ext_vector_type(8))) short short8;
typedef __attribute__((ext_vector_type(4))) float f32x4;

__device__ __forceinline__ ushort_t f2bf(float f) {
  unsigned u = __float_as_uint(f);
  u += 0x7fffu + ((u >> 16) & 1u);   // round-to-nearest-even
  return (ushort_t)(u >> 16);
}
__device__ __forceinline__ float bf_lo(unsigned u) { return __uint_as_float(u << 16); }
__device__ __forceinline__ float bf_hi(unsigned u) { return __uint_as_float(u & 0xffff0000u); }

// async global->LDS, 16B per lane; LDS dst = wave-uniform base + lane*16
__device__ __forceinline__ void gload16(const ushort_t* g, ushort_t* l) {
  __builtin_amdgcn_global_load_lds((const __attribute__((address_space(1))) unsigned int*)g,
                                   (__attribute__((address_space(3))) unsigned int*)l,
                                   16, 0, 0);
}

// relation ids: 0:sc(svc->svc) 1:in(inst->node) 2:ni(node->inst) 3:ii(inst->inst) 4:si(svc->inst) 5:is(inst->svc)
// slots layout (2 edge-stream slices): [rel][slice][dst][cap]
#define SLOTS_TOT 11680000

__device__ __forceinline__ int task_base(int r) {
  const int tb[6] = {0, 20000, 30000, 80000, 130000, 180000};
  return tb[r];
}
__device__ __forceinline__ int od_base(int r) {
  const int ob[6] = {0, 20000, 70000, 80000, 130000, 150000};
  return ob[r];
}

// branchless 6-way select
__device__ __forceinline__ int sel6(int r, int a0, int a1, int a2, int a3, int a4, int a5) {
  int v = a0; v = r == 1 ? a1 : v; v = r == 2 ? a2 : v;
  v = r == 3 ? a3 : v; v = r == 4 ? a4 : v; v = r == 5 ? a5 : v; return v;
}

// ---------------- build: LDS-chunked dst slot build + src histogram ----------------
// REVERTED to R4 (proven): LDS-staged slot chunks, coalesced dump. R6's
// direct-global u16 scatter was 141us (sub-dword RMW scatter + 2.9% occupancy)
// — scattered sub-dword global writes MUST be LDS-staged on this chip.
// Edge stream sliced 2-way: each (chunk, slice) block scans HALF the edges.
// blocks 0..195: dst-side build (chunk = b>>1, slice = b&1)
// blocks 196..213: src-side out_deg partial histograms
#define NB_B2 196
#define NB_H2 18
#define SMEM_BYTES 135168   // max: 'in' chunk 1000*4 + 1000*64*2 = 132000
struct BuildArgs {
  const int* src[6]; const int* dst[6];
  int* od0; int* od1;            // out_deg partials per slice [NTASK]
  int* in_deg0; int* in_deg1;    // dst counts per slice [NTASK]
  ushort_t* slots;
};
__global__ __launch_bounds__(1024) void k_build(BuildArgs a) {
  __shared__ __align__(16) unsigned char smem[SMEM_BYTES];
  int b = blockIdx.x;
  if (b < NB_B2) {
    int s = b & 1, bb = b >> 1;
    // chunk table: sc 14x1500, in 10x1000, ni/ii/si 20x2500, is 14x1500
    int rel = (bb >= 14) + (bb >= 24) + (bb >= 44) + (bb >= 64) + (bb >= 84);
    int ci  = bb - sel6(rel, 0, 14, 24, 44, 64, 84);
    int cs  = sel6(rel, 1500, 1000, 2500, 2500, 2500, 1500);
    int nd  = sel6(rel, 20000, 10000, 50000, 50000, 50000, 20000);
    int cap = sel6(rel, 40, 64, 24, 24, 24, 40);
    int cof = sel6(rel, 0, 1600000, 2880000, 5280000, 7680000, 10080000);
    int ssz = sel6(rel, 800000, 640000, 1200000, 1200000, 1200000, 800000);
    int lo = ci * cs;
    int n = nd - lo; n = n < cs ? n : cs;
    int* cnt = (int*)smem;                         // n ints
    ushort_t* st = (ushort_t*)(smem + n * 4);      // n*cap ushorts
    unsigned* stz = (unsigned*)st;
    for (int i = threadIdx.x; i < n; i += 1024) cnt[i] = 0;
    for (int i = threadIdx.x; i < n * cap / 2; i += 1024) stz[i] = 0;  // src=0 tail: benign
    __syncthreads();
    const int4* d4 = (const int4*)a.dst[rel];
    const int4* s4 = (const int4*)a.src[rel];
    int i1 = (s + 1) * (NEDGE / 8);                // half stream per slice
    for (int i = s * (NEDGE / 8) + threadIdx.x; i < i1; i += 1024) {
      int4 dv = d4[i];
      int4 sv = s4[i];
      int dd[4] = {dv.x, dv.y, dv.z, dv.w};
      int ss[4] = {sv.x, sv.y, sv.z, sv.w};
      #pragma unroll
      for (int j = 0; j < 4; j++) {
        int local = dd[j] - lo;
        if ((unsigned)local < (unsigned)n) {
          int p = atomicAdd(&cnt[local], 1);
          if (p < cap) st[local * cap + p] = (ushort_t)ss[j];
        }
      }
    }
    __syncthreads();
    int* outd = (s ? a.in_deg1 : a.in_deg0) + task_base(rel) + lo;
    for (int i = threadIdx.x; i < n; i += 1024) {
      int c = cnt[i]; outd[i] = c < cap ? c : cap;
    }
    uint4* dp = (uint4*)(a.slots + (size_t)cof + (size_t)s * ssz + (size_t)lo * cap);
    const uint4* sp = (const uint4*)st;
    int n16 = n * cap / 8;                          // exact for all chunks
    for (int i = threadIdx.x; i < n16; i += 1024) dp[i] = sp[i];
    return;
  }
  // src-side out_deg partial histogram; ranges: sc, in0, in1, ni, ii0, ii1, si, is0, is1
  int h = b - NB_B2;
  int s = h & 1, ai = h >> 1;
  int rel = (ai >= 1) + (ai >= 3) + (ai >= 4) + (ai >= 6) + (ai >= 7);
  int lo = (ai == 2 || ai == 5 || ai == 8) ? 25000 : 0;
  int ns = sel6(rel, 20000, 50000, 10000, 50000, 20000, 50000);
  int n = ns - lo; n = n < 25000 ? n : 25000;
  int* cnt = (int*)smem;
  for (int i = threadIdx.x; i < n; i += 1024) cnt[i] = 0;
  __syncthreads();
  const int4* s4 = (const int4*)a.src[rel];
  int i1 = (s + 1) * (NEDGE / 8);
  for (int i = s * (NEDGE / 8) + threadIdx.x; i < i1; i += 1024) {
    int4 v = s4[i];
    int ss[4] = {v.x, v.y, v.z, v.w};
    #pragma unroll
    for (int j = 0; j < 4; j++) {
      int local = ss[j] - lo;
      if ((unsigned)local < (unsigned)n) atomicAdd(&cnt[local], 1);
    }
  }
  __syncthreads();
  int* out = (s ? a.od1 : a.od0) + od_base(rel) + lo;
  for (int i = threadIdx.x; i < n; i += 1024) out[i] = cnt[i];
}

// ---------------- convert: bf16 features + weight transpose + out_deg merge ----------------
struct ConvArgs {
  const float* f0; const float* f1; const float* f2;       // node, inst, svc
  ushort_t* xb0; ushort_t* xb1; ushort_t* xb2;
  const float* W[6];
  ushort_t* Wt_node; ushort_t* Wt_inst; ushort_t* Wt_svc;  // [n][k_cat] row-major
  const int* od0; const int* od1; int* out_deg;
};
__global__ __launch_bounds__(256) void k_convert(ConvArgs a) {
  const int F0 = N_NODE * D / 4, F1 = N_INST * D / 4, F2 = N_SVC * D / 4;
  const int NF = F0 + F1 + F2;        // 2,560,000
  const int WI = 6 * D * D;           // 98,304
  const int MI = NTASK / 4;           // 50,000 int4 merges
  const int total = NF + WI + MI;
  int stride = gridDim.x * 256;
  for (int tid = blockIdx.x * 256 + threadIdx.x; tid < total; tid += stride) {
    if (tid < NF) {
      const float* src; ushort_t* dst; int i;
      if (tid < F0)            { src = a.f0; dst = a.xb0; i = tid; }
      else if (tid < F0 + F1)  { src = a.f1; dst = a.xb1; i = tid - F0; }
      else                     { src = a.f2; dst = a.xb2; i = tid - F0 - F1; }
      float4 v = ((const float4*)src)[i];
      unsigned o0 = (unsigned)f2bf(v.x) | ((unsigned)f2bf(v.y) << 16);
      unsigned o1 = (unsigned)f2bf(v.z) | ((unsigned)f2bf(v.w) << 16);
      ((uint2*)dst)[i] = make_uint2(o0, o1);
    } else if (tid < NF + WI) {
      int wi = tid - NF;
      int r = wi >> 14, idx = wi & 16383;      // D*D = 16384
      int k = idx >> 7, n = idx & 127;
      const float* wp = a.W[0];
      wp = r == 1 ? a.W[1] : wp; wp = r == 2 ? a.W[2] : wp;
      wp = r == 3 ? a.W[3] : wp; wp = r == 4 ? a.W[4] : wp;
      wp = r == 5 ? a.W[5] : wp;
      float v = wp[k * D + n];
      ushort_t* t; int wstride, coff;
      switch (r) {
        case 0: t = a.Wt_svc;  wstride = 256; coff = 0;   break; // sc
        case 1: t = a.Wt_node; wstride = 128; coff = 0;   break; // in
        case 2: t = a.Wt_inst; wstride = 384; coff = 0;   break; // ni
        case 3: t = a.Wt_inst; wstride = 384; coff = 128; break; // ii
        case 4: t = a.Wt_inst; wstride = 384; coff = 256; break; // si
        default:t = a.Wt_svc;  wstride = 256; coff = 128; break; // is
      }
      t[n * wstride + coff + k] = f2bf(v);
    } else {
      int i = tid - NF - WI;
      int4 x = ((const int4*)a.od0)[i];
      int4 y = ((const int4*)a.od1)[i];
      ((int4*)a.out_deg)[i] = make_int4(x.x + y.x, x.y + y.y, x.z + y.z, x.w + y.w);
    }
  }
}

// ---------------- aggregation: one QUAD (16 lanes) per row, 4 rows per wave ----------------
// Inner loop pipelined 4-deep (R4). launch_bounds(256,8): request 8 waves/EU
// (32 waves/CU) — the gather is latency-bound; 58% occupancy was the cap.
struct AggArgs {
  const ushort_t* xb[3];  // 0 node, 1 inst, 2 svc (bf16, [n][128])
  const int* out_deg; const int* in_deg0; const int* in_deg1; const ushort_t* slots;
  ushort_t* agg_node; ushort_t* agg_inst; ushort_t* agg_svc;
};
__global__ __launch_bounds__(256, 8) void k_aggregate(AggArgs a) {
  int wave_g = (blockIdx.x << 2) + (threadIdx.x >> 6);
  int lane = threadIdx.x & 63;
  int q = lane >> 4, l = lane & 15;
  int t = (wave_g << 2) + q;
  if (t >= NTASK) t = NTASK - 1;          // tail quads duplicate last row (benign)

  int rel = (t >= 20000) + (t >= 30000) + (t >= 80000) + (t >= 130000) + (t >= 180000);
  int dst  = t - sel6(rel, 0, 20000, 30000, 80000, 130000, 180000);
  int cap  = sel6(rel, 40, 64, 24, 24, 24, 40);
  int cof  = sel6(rel, 0, 1600000, 2880000, 5280000, 7680000, 10080000);
  int ssz  = sel6(rel, 800000, 640000, 1200000, 1200000, 1200000, 800000);
  int odb  = sel6(rel, 0, 20000, 70000, 80000, 130000, 150000);
  int nsm1 = sel6(rel, 19999, 49999, 9999, 49999, 19999, 49999);
  int sp   = sel6(rel, 2, 1, 0, 1, 2, 1);
  const ushort_t* xb = a.xb[0];
  xb = sp == 1 ? a.xb[1] : xb;
  xb = sp == 2 ? a.xb[2] : xb;

  int d0 = a.in_deg0[t];
  int d1 = a.in_deg1[t];
  int deg = d0 + d1;                       // per-slice counts are cap-clamped
  int base0 = cof + dst * cap;             // slice-0 row
  int base1 = base0 + ssz;                 // slice-1 row
  int l8 = l * 8;                          // channel offset (ushort units)
  int qb = lane & 48;                      // quad's lane base for bpermute
  const ushort_t* xbl = xb + l8;

  // wave-max degree (quads iterate in lockstep; idle quads get scale 0)
  int dmax = deg;
  dmax = max(dmax, __shfl_xor(dmax, 16, 64));
  dmax = max(dmax, __shfl_xor(dmax, 32, 64));
  dmax = __builtin_amdgcn_readfirstlane(dmax);

  float acc[8];
  #pragma unroll
  for (int c = 0; c < 8; c++) acc[c] = 0.f;

#define ACC8(v, sc)                                  \
  do {                                               \
    acc[0] = fmaf(bf_lo((v).x), (sc), acc[0]);       \
    acc[1] = fmaf(bf_hi((v).x), (sc), acc[1]);       \
    acc[2] = fmaf(bf_lo((v).y), (sc), acc[2]);       \
    acc[3] = fmaf(bf_hi((v).y), (sc), acc[3]);       \
    acc[4] = fmaf(bf_lo((v).z), (sc), acc[4]);       \
    acc[5] = fmaf(bf_hi((v).z), (sc), acc[5]);       \
    acc[6] = fmaf(bf_lo((v).w), (sc), acc[6]);       \
    acc[7] = fmaf(bf_hi((v).w), (sc), acc[7]);       \
  } while (0)

  for (int i0 = 0; i0 < dmax; i0 += 16) {
    int nc = deg - i0;                     // this quad's remaining (may be <=0)
    int k = i0 + l;
    k = k < deg ? k : (deg ? deg - 1 : 0); // clamp into valid edge range
    int addr = k < d0 ? base0 + k : base1 + (k - d0);
    int sl = a.slots[addr];                // coalesced u16 within quad
    sl = sl < nsm1 ? sl : nsm1;            // guard garbage (deg==0 rows)
    int od = a.out_deg[odb + sl];          // od>=1 for any real edge
    float scv = (l < nc) ? rsqrtf((float)od) : 0.f;

    int cmax = dmax - i0; cmax = cmax < 16 ? cmax : 16;
    int i = 0;
    for (; i + 4 <= cmax; i += 4) {
      int s0 = __shfl(sl, qb + i,     64);
      int s1 = __shfl(sl, qb + i + 1, 64);
      int s2 = __shfl(sl, qb + i + 2, 64);
      int s3 = __shfl(sl, qb + i + 3, 64);
      float c0 = __shfl(scv, qb + i,     64);
      float c1 = __shfl(scv, qb + i + 1, 64);
      float c2 = __shfl(scv, qb + i + 2, 64);
      float c3 = __shfl(scv, qb + i + 3, 64);
      uint4 v0 = *(const uint4*)(xbl + (size_t)s0 * D);
      uint4 v1 = *(const uint4*)(xbl + (size_t)s1 * D);
      uint4 v2 = *(const uint4*)(xbl + (size_t)s2 * D);
      uint4 v3 = *(const uint4*)(xbl + (size_t)s3 * D);
      ACC8(v0, c0);
      ACC8(v1, c1);
      ACC8(v2, c2);
      ACC8(v3, c3);
    }
    for (; i < cmax; ++i) {
      int s = __shfl(sl, qb + i, 64);      // edge i of THIS quad's row
      float sc = __shfl(scv, qb + i, 64);
      uint4 v = *(const uint4*)(xbl + (size_t)s * D);
      ACC8(v, sc);
    }
  }
#undef ACC8

  float si = rsqrtf((float)(deg < 1 ? 1 : deg));
  ushort_t* o = a.agg_svc;                 // rel 0,5
  o = rel == 1 ? a.agg_node : o;
  o = (rel >= 2 && rel <= 4) ? a.agg_inst : o;
  int stride = sel6(rel, 256, 128, 384, 384, 384, 256);
  int coff   = sel6(rel, 0, 0, 0, 128, 256, 128);
  unsigned e0 = (unsigned)f2bf(acc[0] * si) | ((unsigned)f2bf(acc[1] * si) << 16);
  unsigned e1 = (unsigned)f2bf(acc[2] * si) | ((unsigned)f2bf(acc[3] * si) << 16);
  unsigned e2 = (unsigned)f2bf(acc[4] * si) | ((unsigned)f2bf(acc[5] * si) << 16);
  unsigned e3 = (unsigned)f2bf(acc[6] * si) | ((unsigned)f2bf(acc[7] * si) << 16);
  *(uint4*)(o + (size_t)dst * stride + coff + l8) = make_uint4(e0, e1, e2, e3);
}

// ---------------- fused GEMM + bias + mean + relu ----------------
struct GemmGroup {
  const ushort_t* A; const ushort_t* Wt;
  const float* b0; const float* b1; const float* b2;
  float inv_m; int M; int Kg; int out_base; int tile_begin;
};
struct GemmArgs { GemmGroup g[3]; float* out; };

__global__ __launch_bounds__(256) void k_gemm(GemmArgs ga) {
  int bid = blockIdx.x;
  int gi = (bid >= ga.g[2].tile_begin) ? 2 : (bid >= ga.g[1].tile_begin ? 1 : 0);
  GemmGroup g = ga.g[gi];
  int tile = bid - g.tile_begin;

  __shared__ __align__(16) ushort_t As[128 * 32];   // 8 KB: 128 rows x 32 k (64 B/row)
  __shared__ __align__(16) ushort_t Bs[128 * 32];
  __shared__ float bsum[128];

  if (threadIdx.x < 128) {
    float b = g.b0[threadIdx.x];
    if (g.b1) b += g.b1[threadIdx.x];
    if (g.b2) b += g.b2[threadIdx.x];
    bsum[threadIdx.x] = b;
  }

  int wave = threadIdx.x >> 6, lane = threadIdx.x & 63;
  int wm = (wave >> 1) * 64, wn = (wave & 1) * 64;
  int m16 = lane & 15, kq = lane >> 4;
  int row0 = tile * 128;

  int srow = (wave << 5) + (lane >> 2);              // local row this lane stages (q=0)
  int spg0 = (lane & 3) ^ (srow & 3);                // xor-swizzled global piece
  int ppA = (kq ^ (m16 & 3)) * 8;

  f32x4 acc[4][4] = {};

  for (int kc = 0; kc < g.Kg; kc += 32) {
    __syncthreads();
    #pragma unroll
    for (int qq = 0; qq < 2; qq++) {
      int rloc = srow + qq * 16;
      int grA = row0 + rloc; grA = grA < g.M ? grA : g.M - 1;
      gload16(g.A  + (size_t)grA * g.Kg + kc + spg0 * 8, &As[((wave << 5) + (qq << 4)) << 5]);
      gload16(g.Wt + (size_t)rloc * g.Kg + kc + spg0 * 8, &Bs[((wave << 5) + (qq << 4)) << 5]);
    }
    __syncthreads();
    short8 av[4], bv[4];
    #pragma unroll
    for (int i = 0; i < 4; i++) av[i] = *(const short8*)(&As[((wm + i * 16 + m16) << 5) + ppA]);
    #pragma unroll
    for (int j = 0; j < 4; j++) bv[j] = *(const short8*)(&Bs[((wn + j * 16 + m16) << 5) + ppA]);
    #pragma unroll
    for (int i = 0; i < 4; i++)
      #pragma unroll
      for (int j = 0; j < 4; j++)
        acc[i][j] = __builtin_amdgcn_mfma_f32_16x16x32_bf16(av[i], bv[j], acc[i][j], 0, 0, 0);
  }

  // epilogue: D[row=(lane>>4)*4+r][col=lane&15] per 16x16 tile
  #pragma unroll
  for (int i = 0; i < 4; i++) {
    #pragma unroll
    for (int j = 0; j < 4; j++) {
      int col = wn + j * 16 + m16;
      #pragma unroll
      for (int r = 0; r < 4; r++) {
        int row = wm + i * 16 + kq * 4 + r;
        int gr = row0 + row;
        if (gr < g.M) {
          float v = (acc[i][j][r] + bsum[col]) * g.inv_m;
          v = v > 0.f ? v : 0.f;
          ga.out[(size_t)(g.out_base + gr) * D + col] = v;
        }
      }
    }
  }
}

// ---------------- host ----------------
extern "C" void kernel_launch(void* const* d_in, const int* in_sizes, int n_in,
                              void* d_out, int out_size, void* d_ws, size_t ws_size,
                              hipStream_t stream) {
  const float* node_feat = (const float*)d_in[0];
  const float* inst_feat = (const float*)d_in[1];
  const float* svc_feat  = (const float*)d_in[2];
  const int* e_src[6]; const int* e_dst[6]; const float* W[6]; const float* B[6];
  for (int r = 0; r < 6; r++) {
    e_src[r] = (const int*)d_in[3 + 4 * r];
    e_dst[r] = (const int*)d_in[4 + 4 * r];
    W[r]     = (const float*)d_in[5 + 4 * r];
    B[r]     = (const float*)d_in[6 + 4 * r];
  }

  char* ws = (char*)d_ws;
  size_t off = 0;
  auto alloc = [&](size_t bytes) { char* p = ws + off; off += (bytes + 255) & ~(size_t)255; return p; };
  ushort_t* xb_node  = (ushort_t*)alloc((size_t)N_NODE * D * 2);
  ushort_t* xb_inst  = (ushort_t*)alloc((size_t)N_INST * D * 2);
  ushort_t* xb_svc   = (ushort_t*)alloc((size_t)N_SVC  * D * 2);
  ushort_t* Wt_node  = (ushort_t*)alloc(128 * 128 * 2);
  ushort_t* Wt_inst  = (ushort_t*)alloc(128 * 384 * 2);
  ushort_t* Wt_svc   = (ushort_t*)alloc(128 * 256 * 2);
  ushort_t* agg_node = (ushort_t*)alloc((size_t)N_NODE * 128 * 2);
  ushort_t* agg_inst = (ushort_t*)alloc((size_t)N_INST * 384 * 2);
  ushort_t* agg_svc  = (ushort_t*)alloc((size_t)N_SVC  * 256 * 2);
  int* in_deg0 = (int*)alloc(NTASK * 4);
  int* in_deg1 = (int*)alloc(NTASK * 4);
  int* od0     = (int*)alloc(NTASK * 4);
  int* od1     = (int*)alloc(NTASK * 4);
  int* out_deg = (int*)alloc(NTASK * 4);
  ushort_t* slots = (ushort_t*)alloc((size_t)SLOTS_TOT * 2);

  // 1. build: 196 sliced dst-build blocks + 18 sliced src-hist blocks (one round)
  {
    BuildArgs a;
    for (int r = 0; r < 6; r++) { a.src[r] = e_src[r]; a.dst[r] = e_dst[r]; }
    a.od0 = od0; a.od1 = od1; a.in_deg0 = in_deg0; a.in_deg1 = in_deg1; a.slots = slots;
    k_build<<<NB_B2 + NB_H2, 1024, 0, stream>>>(a);
  }
  // 2. convert: full-occupancy streaming (features, weights, out_deg merge)
  {
    ConvArgs a;
    a.f0 = node_feat; a.f1 = inst_feat; a.f2 = svc_feat;
    a.xb0 = xb_node; a.xb1 = xb_inst; a.xb2 = xb_svc;
    for (int r = 0; r < 6; r++) a.W[r] = W[r];
    a.Wt_node = Wt_node; a.Wt_inst = Wt_inst; a.Wt_svc = Wt_svc;
    a.od0 = od0; a.od1 = od1; a.out_deg = out_deg;
    k_convert<<<2048, 256, 0, stream>>>(a);
  }
  // 3. aggregate: 4 rows per wave, 16 rows per block
  {
    AggArgs a;
    a.xb[0] = xb_node; a.xb[1] = xb_inst; a.xb[2] = xb_svc;
    a.out_deg = out_deg; a.in_deg0 = in_deg0; a.in_deg1 = in_deg1; a.slots = slots;
    a.agg_node = agg_node; a.agg_inst = agg_inst; a.agg_svc = agg_svc;
    k_aggregate<<<(NTASK + 15) / 16, 256, 0, stream>>>(a);
  }
  // 4. fused GEMM
  {
    GemmArgs ga;
    ga.out = (float*)d_out;
    int t_node = (N_NODE + 127) / 128;   // 79
    int t_inst = (N_INST + 127) / 128;   // 391
    int t_svc  = (N_SVC  + 127) / 128;   // 157
    ga.g[0] = { agg_node, Wt_node, B[1], nullptr, nullptr, 1.0f,        N_NODE, 128, 0,               0 };
    ga.g[1] = { agg_inst, Wt_inst, B[2], B[3],    B[4],    1.0f / 3.0f, N_INST, 384, N_NODE,          t_node };
    ga.g[2] = { agg_svc,  Wt_svc,  B[0], B[5],    nullptr, 0.5f,        N_SVC,  256, N_NODE + N_INST, t_node + t_inst };
    k_gemm<<<t_node + t_inst + t_svc, 256, 0, stream>>>(ga);
  }
}